// Round 2
// baseline (256.628 us; speedup 1.0000x reference)
//
#include <hip/hip_runtime.h>

// Problem constants
#define G   128
#define A   100
#define WIN 10
#define FD  16
#define H   128
#define NROWS (G*A)          // 12800
#define K1  (WIN*FD)         // 160

// ---------------------------------------------------------------------------
// Kernel 1: per-group normalized adjacency (symmetric output!)
//   2x2 tiles over the corr matrix, w-major centered returns in LDS.
// ---------------------------------------------------------------------------
__global__ __launch_bounds__(256) void k_nadj(const float* __restrict__ x,
                                              float* __restrict__ nadj) {
    __shared__ float xcT[WIN][104];    // w-major, padded
    __shared__ float invn[A];
    __shared__ float adjs[A][101];     // pad 101: conflict-free row reads
    __shared__ float dinv[A];
    const int g = blockIdx.x;
    const int t = threadIdx.x;

    for (int idx = t; idx < A * WIN; idx += 256) {
        int a = idx / WIN, w = idx % WIN;
        xcT[w][a] = x[((g * A + a) * WIN + w) * FD + (FD - 1)];
    }
    __syncthreads();
    if (t < A) {
        float m = 0.f;
        #pragma unroll
        for (int w = 0; w < WIN; w++) m += xcT[w][t];
        m *= (1.0f / WIN);
        float ss = 0.f;
        #pragma unroll
        for (int w = 0; w < WIN; w++) {
            float v = xcT[w][t] - m;
            xcT[w][t] = v;
            ss += v * v;
        }
        invn[t] = rsqrtf(ss);
    }
    __syncthreads();
    // 50x50 2x2 tiles
    for (int tt2 = t; tt2 < 2500; tt2 += 256) {
        int ti = tt2 / 50, tj = tt2 % 50;
        int i0 = 2 * ti, j0v = 2 * tj;
        float d00 = 0.f, d01 = 0.f, d10 = 0.f, d11 = 0.f;
        #pragma unroll
        for (int w = 0; w < WIN; w++) {
            float2 xi = *(const float2*)&xcT[w][i0];
            float2 xj = *(const float2*)&xcT[w][j0v];
            d00 = fmaf(xi.x, xj.x, d00); d01 = fmaf(xi.x, xj.y, d01);
            d10 = fmaf(xi.y, xj.x, d10); d11 = fmaf(xi.y, xj.y, d11);
        }
        float ii0 = invn[i0], ii1 = invn[i0 + 1];
        float ij0 = invn[j0v], ij1 = invn[j0v + 1];
        float e = (ti == tj) ? 1.f : 0.f;   // diagonal hits d00 and d11 only
        adjs[i0][j0v]         = 1.f - fabsf(d00 * ii0 * ij0) + e;
        adjs[i0][j0v + 1]     = 1.f - fabsf(d01 * ii0 * ij1);
        adjs[i0 + 1][j0v]     = 1.f - fabsf(d10 * ii1 * ij0);
        adjs[i0 + 1][j0v + 1] = 1.f - fabsf(d11 * ii1 * ij1) + e;
    }
    __syncthreads();
    if (t < A) {
        float s = 0.f;
        for (int j = 0; j < A; j++) s += adjs[t][j];
        dinv[t] = rsqrtf(s);
    }
    __syncthreads();
    for (int idx = t; idx < A * A; idx += 256) {
        int i = idx / A, j = idx % A;
        nadj[g * A * A + idx] = dinv[i] * adjs[i][j] * dinv[j];
    }
}

// ---------------------------------------------------------------------------
// Kernel 2: Y = X @ W   (X: [NROWS, K], W: [K, 128])
// BM=64, BK=16; 256 threads; 4r x 8c register tile; X transposed in LDS so
// both operands are ds_read_b128.
// ---------------------------------------------------------------------------
__global__ __launch_bounds__(256) void k_gemm(const float* __restrict__ X,
                                              const float* __restrict__ W,
                                              float* __restrict__ Y, int K) {
    __shared__ float XsT[16][64];    // [k][r]
    __shared__ float Ws[16][H];      // [k][c]
    const int t = threadIdx.x;
    const int n0 = blockIdx.x * 64;
    const int cg = t & 15, rg = t >> 4;      // 16 x 16
    const int c0 = cg * 8;
    const int r0 = rg * 4;

    float acc[4][8] = {};

    for (int k0 = 0; k0 < K; k0 += 16) {
        {   // stage X transposed: 64 rows x 16 k
            int r = t >> 2, kq = t & 3;
            float4 xv = *(const float4*)(X + (size_t)(n0 + r) * K + k0 + kq * 4);
            XsT[kq * 4 + 0][r] = xv.x;
            XsT[kq * 4 + 1][r] = xv.y;
            XsT[kq * 4 + 2][r] = xv.z;
            XsT[kq * 4 + 3][r] = xv.w;
        }
        #pragma unroll
        for (int i = 0; i < 2; i++) {    // stage W: 16 x 128
            int e = t + i * 256;
            int kk = e >> 5, c4 = (e & 31) * 4;
            *(float4*)(&Ws[kk][c4]) = *(const float4*)(W + (size_t)(k0 + kk) * H + c4);
        }
        __syncthreads();
        #pragma unroll
        for (int k = 0; k < 16; k++) {
            float4 a  = *(const float4*)(&XsT[k][r0]);
            float4 b0 = *(const float4*)(&Ws[k][c0]);
            float4 b1 = *(const float4*)(&Ws[k][c0 + 4]);
            float av[4] = {a.x, a.y, a.z, a.w};
            #pragma unroll
            for (int i = 0; i < 4; i++) {
                acc[i][0] = fmaf(av[i], b0.x, acc[i][0]);
                acc[i][1] = fmaf(av[i], b0.y, acc[i][1]);
                acc[i][2] = fmaf(av[i], b0.z, acc[i][2]);
                acc[i][3] = fmaf(av[i], b0.w, acc[i][3]);
                acc[i][4] = fmaf(av[i], b1.x, acc[i][4]);
                acc[i][5] = fmaf(av[i], b1.y, acc[i][5]);
                acc[i][6] = fmaf(av[i], b1.z, acc[i][6]);
                acc[i][7] = fmaf(av[i], b1.w, acc[i][7]);
            }
        }
        __syncthreads();
    }
    #pragma unroll
    for (int i = 0; i < 4; i++) {
        float* yp = Y + (size_t)(n0 + r0 + i) * H + c0;
        *(float4*)yp       = make_float4(acc[i][0], acc[i][1], acc[i][2], acc[i][3]);
        *(float4*)(yp + 4) = make_float4(acc[i][4], acc[i][5], acc[i][6], acc[i][7]);
    }
}

// ---------------------------------------------------------------------------
// Kernel 3: Z[g,i,:] = relu(b + sum_j nadj[g,i,j] * Y[g,j,:])
// nadj is SYMMETRIC -> nadj[g,i0..i0+7, j] == nadj[g, j, i0..i0+7] which is
// contiguous and wave-uniform: fetch via forced-scalar loads. Y slab in LDS,
// read as float2 (2 cols per lane). 8 rows per wave; grid (G, 2 row-halves).
// ---------------------------------------------------------------------------
__global__ __launch_bounds__(448) void k_agg(const float* __restrict__ nadj,
                                             const float* __restrict__ Y,
                                             const float* __restrict__ bias,
                                             float* __restrict__ Z) {
    __shared__ float Ys[A][H];        // 51.2 KB
    const int g = blockIdx.x;
    const int half = blockIdx.y;
    const int t = threadIdx.x;

    const float* Yg = Y + (size_t)g * A * H;
    for (int i = t; i < A * H / 4; i += 448)
        ((float4*)Ys)[i] = ((const float4*)Yg)[i];
    __syncthreads();

    const int wv = t >> 6, lane = t & 63;
    const int i0 = __builtin_amdgcn_readfirstlane(half * 56 + wv * 8);
    const int c0 = lane * 2;
    const float* np = nadj + (size_t)g * A * A + i0;

    float acc[8][2] = {};
    #pragma unroll 2
    for (int j = 0; j < A; j++) {
        float2 yv = *(const float2*)(&Ys[j][c0]);
        const float* nr = np + (size_t)j * A;   // uniform address -> s_load
        #pragma unroll
        for (int r = 0; r < 8; r++) {
            float nv = nr[r];
            acc[r][0] = fmaf(nv, yv.x, acc[r][0]);
            acc[r][1] = fmaf(nv, yv.y, acc[r][1]);
        }
    }
    float2 bv = *(const float2*)(bias + c0);
    #pragma unroll
    for (int r = 0; r < 8; r++) {
        int i = i0 + r;
        if (i < A) {
            float2 o;
            o.x = fmaxf(0.f, acc[r][0] + bv.x);
            o.y = fmaxf(0.f, acc[r][1] + bv.y);
            *(float2*)(Z + ((size_t)g * A + i) * H + c0) = o;
        }
    }
}

// ---------------------------------------------------------------------------
// Kernel 4: fused conv1(1x3) + relu + conv2(1x3), both padded along H.
// Lane = (row, 8-col chunk); fully register-resident, no shuffles.
// Weights packed once into LDS [c][8] = {w0,w1,w2,b1, v0,v1,v2,0}.
// ---------------------------------------------------------------------------
__global__ __launch_bounds__(128) void k_conv(const float* __restrict__ h3,
                                              const float* __restrict__ cw1,
                                              const float* __restrict__ cb1,
                                              const float* __restrict__ cw2,
                                              const float* __restrict__ cb2,
                                              float* __restrict__ out) {
    __shared__ float wbuf[H][8];     // 4 KB
    const int t = threadIdx.x;
    if (t < H) {
        wbuf[t][0] = cw1[3 * t];
        wbuf[t][1] = cw1[3 * t + 1];
        wbuf[t][2] = cw1[3 * t + 2];
        wbuf[t][3] = cb1[t];
        wbuf[t][4] = cw2[3 * t];
        wbuf[t][5] = cw2[3 * t + 1];
        wbuf[t][6] = cw2[3 * t + 2];
        wbuf[t][7] = 0.f;
    }
    __syncthreads();

    const int gid = blockIdx.x * 128 + t;
    const int n = gid >> 4;
    const int j0 = (gid & 15) << 3;
    const float* hr = h3 + (size_t)n * H;

    float hh[12];    // h[j0-2 .. j0+9], zero-padded (conv1 padding)
    #pragma unroll
    for (int k = 0; k < 12; k++) {
        int j = j0 - 2 + k;
        hh[k] = (j >= 0 && j < H) ? hr[j] : 0.f;
    }
    const float mlo = (j0 == 0)     ? 0.f : 1.f;  // conv2 zero-pad: T[-1]=0
    const float mhi = (j0 == H - 8) ? 0.f : 1.f;  // T[128]=0
    const float c2b = cb2[0];

    float acc[8] = {};
    #pragma unroll 4
    for (int c = 0; c < H; c++) {
        float4 wA = *(const float4*)(&wbuf[c][0]);  // w0,w1,w2,b
        float4 wB = *(const float4*)(&wbuf[c][4]);  // v0,v1,v2,-
        float tt[10];   // t at j = j0-1+m
        #pragma unroll
        for (int m = 0; m < 10; m++)
            tt[m] = fmaxf(0.f, fmaf(wA.z, hh[m + 2],
                             fmaf(wA.y, hh[m + 1],
                             fmaf(wA.x, hh[m], wA.w))));
        tt[0] *= mlo;
        tt[9] *= mhi;
        #pragma unroll
        for (int q = 0; q < 8; q++)
            acc[q] = fmaf(wB.x, tt[q],
                     fmaf(wB.y, tt[q + 1],
                     fmaf(wB.z, tt[q + 2], acc[q])));
    }
    float* op = out + (size_t)n * H + j0;
    *(float4*)op       = make_float4(acc[0] + c2b, acc[1] + c2b, acc[2] + c2b, acc[3] + c2b);
    *(float4*)(op + 4) = make_float4(acc[4] + c2b, acc[5] + c2b, acc[6] + c2b, acc[7] + c2b);
}

// ---------------------------------------------------------------------------
extern "C" void kernel_launch(void* const* d_in, const int* in_sizes, int n_in,
                              void* d_out, int out_size, void* d_ws, size_t ws_size,
                              hipStream_t stream) {
    const float* x   = (const float*)d_in[0];
    const float* W1  = (const float*)d_in[1];
    const float* b1  = (const float*)d_in[2];
    const float* W2  = (const float*)d_in[3];
    const float* b2  = (const float*)d_in[4];
    const float* W3  = (const float*)d_in[5];
    const float* b3  = (const float*)d_in[6];
    const float* cw1 = (const float*)d_in[7];
    const float* cb1 = (const float*)d_in[8];
    const float* cw2 = (const float*)d_in[9];
    const float* cb2 = (const float*)d_in[10];
    float* out = (float*)d_out;

    float* ws   = (float*)d_ws;
    float* nadj = ws;                         // G*A*A      = 1,280,000 floats
    float* bufY = nadj + (size_t)G * A * A;   // NROWS*H    = 1,638,400 floats
    float* bufZ = bufY + (size_t)NROWS * H;   // NROWS*H

    k_nadj<<<G, 256, 0, stream>>>(x, nadj);

    // Layer 1: Y = feats @ W1 ; Z = relu(nadj @ Y + b1)
    k_gemm<<<NROWS / 64, 256, 0, stream>>>(x, W1, bufY, K1);
    k_agg<<<dim3(G, 2), 448, 0, stream>>>(nadj, bufY, b1, bufZ);

    // Layer 2
    k_gemm<<<NROWS / 64, 256, 0, stream>>>(bufZ, W2, bufY, H);
    k_agg<<<dim3(G, 2), 448, 0, stream>>>(nadj, bufY, b2, bufZ);

    // Layer 3
    k_gemm<<<NROWS / 64, 256, 0, stream>>>(bufZ, W3, bufY, H);
    k_agg<<<dim3(G, 2), 448, 0, stream>>>(nadj, bufY, b3, bufZ);

    // Fused conv1 + relu + conv2
    k_conv<<<(NROWS * 16) / 128, 128, 0, stream>>>(bufZ, cw1, cb1, cw2, cb2, out);
}

// Round 3
// 225.049 us; speedup vs baseline: 1.1403x; 1.1403x over previous
//
#include <hip/hip_runtime.h>

// Problem constants
#define G   128
#define A   100
#define WIN 10
#define FD  16
#define H   128
#define NROWS (G*A)          // 12800
#define K1  (WIN*FD)         // 160

// ---------------------------------------------------------------------------
// Kernel 1: per-group normalized adjacency (symmetric), 2x2 corr tiles.
// ---------------------------------------------------------------------------
__global__ __launch_bounds__(256) void k_nadj(const float* __restrict__ x,
                                              float* __restrict__ nadj) {
    __shared__ float xcT[WIN][104];    // w-major, padded
    __shared__ float invn[A];
    __shared__ float adjs[A][101];
    __shared__ float dinv[A];
    const int g = blockIdx.x;
    const int t = threadIdx.x;

    for (int idx = t; idx < A * WIN; idx += 256) {
        int a = idx / WIN, w = idx % WIN;
        xcT[w][a] = x[((g * A + a) * WIN + w) * FD + (FD - 1)];
    }
    __syncthreads();
    if (t < A) {
        float m = 0.f;
        #pragma unroll
        for (int w = 0; w < WIN; w++) m += xcT[w][t];
        m *= (1.0f / WIN);
        float ss = 0.f;
        #pragma unroll
        for (int w = 0; w < WIN; w++) {
            float v = xcT[w][t] - m;
            xcT[w][t] = v;
            ss += v * v;
        }
        invn[t] = rsqrtf(ss);
    }
    __syncthreads();
    for (int tt2 = t; tt2 < 2500; tt2 += 256) {
        int ti = tt2 / 50, tj = tt2 % 50;
        int i0 = 2 * ti, j0v = 2 * tj;
        float d00 = 0.f, d01 = 0.f, d10 = 0.f, d11 = 0.f;
        #pragma unroll
        for (int w = 0; w < WIN; w++) {
            float2 xi = *(const float2*)&xcT[w][i0];
            float2 xj = *(const float2*)&xcT[w][j0v];
            d00 = fmaf(xi.x, xj.x, d00); d01 = fmaf(xi.x, xj.y, d01);
            d10 = fmaf(xi.y, xj.x, d10); d11 = fmaf(xi.y, xj.y, d11);
        }
        float ii0 = invn[i0], ii1 = invn[i0 + 1];
        float ij0 = invn[j0v], ij1 = invn[j0v + 1];
        float e = (ti == tj) ? 1.f : 0.f;
        adjs[i0][j0v]         = 1.f - fabsf(d00 * ii0 * ij0) + e;
        adjs[i0][j0v + 1]     = 1.f - fabsf(d01 * ii0 * ij1);
        adjs[i0 + 1][j0v]     = 1.f - fabsf(d10 * ii1 * ij0);
        adjs[i0 + 1][j0v + 1] = 1.f - fabsf(d11 * ii1 * ij1) + e;
    }
    __syncthreads();
    if (t < A) {
        float s = 0.f;
        for (int j = 0; j < A; j++) s += adjs[t][j];
        dinv[t] = rsqrtf(s);
    }
    __syncthreads();
    for (int idx = t; idx < A * A; idx += 256) {
        int i = idx / A, j = idx % A;
        nadj[g * A * A + idx] = dinv[i] * adjs[i][j] * dinv[j];
    }
}

// ---------------------------------------------------------------------------
// Kernel 2: one GCN layer, fused: Z[g,:,cbase:cbase+64] =
//   relu(nadj[g] @ (X[g] @ W[:,cbase:+64]) + b[cbase:+64])
// Grid (G, 2 col-halves), 512 threads. Y tile stays in LDS (no HBM trip).
// Thread tile: 4 rows (ty+32m) x 4 cols. Rows 100..127 computed as garbage,
// masked at the final store (keeps inner loops unmasked).
// ---------------------------------------------------------------------------
__global__ __launch_bounds__(512) void k_layer(const float* __restrict__ nadj,
                                               const float* __restrict__ X,
                                               const float* __restrict__ W,
                                               const float* __restrict__ bias,
                                               float* __restrict__ Z, int K) {
    __shared__ float ns[A][104];      // 41.6 KB
    __shared__ float Ys[128][68];     // 34.8 KB
    __shared__ float Xs[128][34];     // 17.4 KB
    __shared__ float Ws[32][68];      //  8.7 KB   (total ~100 KB)
    const int g = blockIdx.x;
    const int cbase = blockIdx.y * 64;
    const int t = threadIdx.x;
    const int tx = t & 15, ty = t >> 4;      // 16 x 32
    const int c0 = tx * 4;

    // stage nadj[g] (used only in phase B; phase-A syncs cover the hazard)
    const float* ng = nadj + (size_t)g * A * A;
    for (int e = t; e < A * A / 2; e += 512) {
        int i = e / 50, j2 = (e - i * 50) * 2;
        *(float2*)&ns[i][j2] = *(const float2*)(ng + i * A + j2);
    }

    float acc[4][4] = {};
    const float* Xg = X + (size_t)g * A * K;

    for (int k0 = 0; k0 < K; k0 += 32) {
        // stage Xs: 100 rows x 32 k (1600 float2)
        for (int e = t; e < 1600; e += 512) {
            int r = e >> 4, c2 = (e & 15) * 2;
            *(float2*)&Xs[r][c2] = *(const float2*)(Xg + (size_t)r * K + k0 + c2);
        }
        // stage Ws: 32 x 64 (512 float4)
        {
            int r = t >> 4, c4 = (t & 15) * 4;
            *(float4*)&Ws[r][c4] = *(const float4*)(W + (size_t)(k0 + r) * H + cbase + c4);
        }
        __syncthreads();
        #pragma unroll 4
        for (int kk = 0; kk < 32; kk += 2) {
            float4 w0 = *(const float4*)&Ws[kk][c0];
            float4 w1 = *(const float4*)&Ws[kk + 1][c0];
            #pragma unroll
            for (int m = 0; m < 4; m++) {
                float2 xv = *(const float2*)&Xs[ty + 32 * m][kk];
                acc[m][0] = fmaf(xv.x, w0.x, fmaf(xv.y, w1.x, acc[m][0]));
                acc[m][1] = fmaf(xv.x, w0.y, fmaf(xv.y, w1.y, acc[m][1]));
                acc[m][2] = fmaf(xv.x, w0.z, fmaf(xv.y, w1.z, acc[m][2]));
                acc[m][3] = fmaf(xv.x, w0.w, fmaf(xv.y, w1.w, acc[m][3]));
            }
        }
        __syncthreads();
    }

    // Y tile -> LDS
    #pragma unroll
    for (int m = 0; m < 4; m++) {
        *(float4*)&Ys[ty + 32 * m][c0] =
            make_float4(acc[m][0], acc[m][1], acc[m][2], acc[m][3]);
        acc[m][0] = acc[m][1] = acc[m][2] = acc[m][3] = 0.f;
    }
    __syncthreads();

    // phase B: Z = relu(ns @ Ys + b)
    #pragma unroll 2
    for (int j = 0; j < A; j += 2) {
        float4 y0 = *(const float4*)&Ys[j][c0];
        float4 y1 = *(const float4*)&Ys[j + 1][c0];
        #pragma unroll
        for (int m = 0; m < 4; m++) {
            float2 nv = *(const float2*)&ns[ty + 32 * m][j];
            acc[m][0] = fmaf(nv.x, y0.x, fmaf(nv.y, y1.x, acc[m][0]));
            acc[m][1] = fmaf(nv.x, y0.y, fmaf(nv.y, y1.y, acc[m][1]));
            acc[m][2] = fmaf(nv.x, y0.z, fmaf(nv.y, y1.z, acc[m][2]));
            acc[m][3] = fmaf(nv.x, y0.w, fmaf(nv.y, y1.w, acc[m][3]));
        }
    }
    float4 bv = *(const float4*)(bias + cbase + c0);
    #pragma unroll
    for (int m = 0; m < 4; m++) {
        int r = ty + 32 * m;
        if (r < A) {
            float4 o;
            o.x = fmaxf(0.f, acc[m][0] + bv.x);
            o.y = fmaxf(0.f, acc[m][1] + bv.y);
            o.z = fmaxf(0.f, acc[m][2] + bv.z);
            o.w = fmaxf(0.f, acc[m][3] + bv.w);
            *(float4*)(Z + ((size_t)g * A + r) * H + cbase + c0) = o;
        }
    }
}

// ---------------------------------------------------------------------------
// Kernel 3: fused conv1(1x3)+relu+conv2(1x3). 4 output cols per lane,
// channel range split across wave pairs (c-halves), combined via LDS.
// No shuffles; 6 conv1 taps recomputed per lane. Weights via s_loads.
// ---------------------------------------------------------------------------
__global__ __launch_bounds__(256) void k_conv(const float* __restrict__ h3,
                                              const float* cw1, const float* cb1,
                                              const float* cw2, const float* cb2,
                                              float* __restrict__ out) {
    __shared__ float part[2][64][4];   // 2 KB
    const int t = threadIdx.x;
    const int wv = t >> 6, lane = t & 63;
    const int rowset = wv >> 1, chalf = wv & 1;
    const int n = blockIdx.x * 4 + rowset * 2 + (lane >> 5);
    const int q = lane & 31;
    const int j0 = q * 4;
    const float* hr = h3 + (size_t)n * H;

    float hh[8];   // h[j0-2 .. j0+5], zero-padded (conv1 padding)
    if (q == 0) {
        float4 a  = *(const float4*)(hr);
        float2 b2 = *(const float2*)(hr + 4);
        hh[0] = 0.f;  hh[1] = 0.f;  hh[2] = a.x; hh[3] = a.y;
        hh[4] = a.z;  hh[5] = a.w;  hh[6] = b2.x; hh[7] = b2.y;
    } else if (q == 31) {
        float2 b2 = *(const float2*)(hr + 122);
        float4 a  = *(const float4*)(hr + 124);
        hh[0] = b2.x; hh[1] = b2.y; hh[2] = a.x; hh[3] = a.y;
        hh[4] = a.z;  hh[5] = a.w;  hh[6] = 0.f; hh[7] = 0.f;
    } else {
        float4 a  = *(const float4*)(hr + j0 - 2);
        float4 b4 = *(const float4*)(hr + j0 + 2);
        hh[0] = a.x;  hh[1] = a.y;  hh[2] = a.z;  hh[3] = a.w;
        hh[4] = b4.x; hh[5] = b4.y; hh[6] = b4.z; hh[7] = b4.w;
    }
    const float mlo = (q == 0)  ? 0.f : 1.f;   // conv2 pad: T[-1]=0
    const float mhi = (q == 31) ? 0.f : 1.f;   // T[128]=0

    const int cA = chalf * 64, cB = cA + 64;
    float acc[4] = {0.f, 0.f, 0.f, 0.f};
    #pragma unroll 2
    for (int c = cA; c < cB; c++) {
        float w0 = cw1[3 * c], w1 = cw1[3 * c + 1], w2 = cw1[3 * c + 2];
        float b  = cb1[c];
        float v0 = cw2[3 * c], v1 = cw2[3 * c + 1], v2 = cw2[3 * c + 2];
        float tt[6];   // conv1 output at j = j0-1+m
        #pragma unroll
        for (int m = 0; m < 6; m++)
            tt[m] = fmaxf(0.f, fmaf(w2, hh[m + 2],
                               fmaf(w1, hh[m + 1],
                               fmaf(w0, hh[m], b))));
        tt[0] *= mlo;
        tt[5] *= mhi;
        #pragma unroll
        for (int p = 0; p < 4; p++)
            acc[p] = fmaf(v0, tt[p],
                     fmaf(v1, tt[p + 1],
                     fmaf(v2, tt[p + 2], acc[p])));
    }
    if (chalf == 1)
        *(float4*)&part[rowset][lane][0] = make_float4(acc[0], acc[1], acc[2], acc[3]);
    __syncthreads();
    if (chalf == 0) {
        float4 p = *(const float4*)&part[rowset][lane][0];
        float c2b = cb2[0];
        float4 o = make_float4(acc[0] + p.x + c2b, acc[1] + p.y + c2b,
                               acc[2] + p.z + c2b, acc[3] + p.w + c2b);
        *(float4*)(out + (size_t)n * H + j0) = o;
    }
}

// ---------------------------------------------------------------------------
extern "C" void kernel_launch(void* const* d_in, const int* in_sizes, int n_in,
                              void* d_out, int out_size, void* d_ws, size_t ws_size,
                              hipStream_t stream) {
    const float* x   = (const float*)d_in[0];
    const float* W1  = (const float*)d_in[1];
    const float* b1  = (const float*)d_in[2];
    const float* W2  = (const float*)d_in[3];
    const float* b2  = (const float*)d_in[4];
    const float* W3  = (const float*)d_in[5];
    const float* b3  = (const float*)d_in[6];
    const float* cw1 = (const float*)d_in[7];
    const float* cb1 = (const float*)d_in[8];
    const float* cw2 = (const float*)d_in[9];
    const float* cb2 = (const float*)d_in[10];
    float* out = (float*)d_out;

    float* ws   = (float*)d_ws;
    float* nadj = ws;                         // G*A*A   = 1,280,000 floats
    float* bufA = nadj + (size_t)G * A * A;   // NROWS*H = 1,638,400 floats
    float* bufB = bufA + (size_t)NROWS * H;

    k_nadj<<<G, 256, 0, stream>>>(x, nadj);

    k_layer<<<dim3(G, 2), 512, 0, stream>>>(nadj, x,    W1, b1, bufA, K1);
    k_layer<<<dim3(G, 2), 512, 0, stream>>>(nadj, bufA, W2, b2, bufB, H);
    k_layer<<<dim3(G, 2), 512, 0, stream>>>(nadj, bufB, W3, b3, bufA, H);

    k_conv<<<NROWS / 4, 256, 0, stream>>>(bufA, cw1, cb1, cw2, cb2, out);
}

// Round 5
// 197.025 us; speedup vs baseline: 1.3025x; 1.1422x over previous
//
#include <hip/hip_runtime.h>

// Problem constants
#define G   128
#define A   100
#define WIN 10
#define FD  16
#define H   128
#define NROWS (G*A)          // 12800
#define K1  (WIN*FD)         // 160

typedef __attribute__((ext_vector_type(8))) short short8;
typedef __attribute__((ext_vector_type(4))) short short4v;
typedef __attribute__((ext_vector_type(4))) float floatx4;

struct BfPair { short h, l; };

__device__ inline unsigned short f2bf(float f) {   // RNE fp32 -> bf16
    unsigned u = __float_as_uint(f);
    u += 0x7fff + ((u >> 16) & 1);
    return (unsigned short)(u >> 16);
}
__device__ inline float bf2f(unsigned short h) {
    return __uint_as_float(((unsigned)h) << 16);
}
__device__ inline BfPair split1(float v) {
    BfPair p;
    unsigned short hb = f2bf(v);
    p.h = (short)hb;
    p.l = (short)f2bf(v - bf2f(hb));
    return p;
}

// ---------------------------------------------------------------------------
// Kernel 1: per-group normalized adjacency (symmetric), 2x2 corr tiles.
// ---------------------------------------------------------------------------
__global__ __launch_bounds__(256) void k_nadj(const float* __restrict__ x,
                                              float* __restrict__ nadj) {
    __shared__ float xcT[WIN][104];
    __shared__ float invn[A];
    __shared__ float adjs[A][101];
    __shared__ float dinv[A];
    const int g = blockIdx.x;
    const int t = threadIdx.x;

    for (int idx = t; idx < A * WIN; idx += 256) {
        int a = idx / WIN, w = idx % WIN;
        xcT[w][a] = x[((g * A + a) * WIN + w) * FD + (FD - 1)];
    }
    __syncthreads();
    if (t < A) {
        float m = 0.f;
        #pragma unroll
        for (int w = 0; w < WIN; w++) m += xcT[w][t];
        m *= (1.0f / WIN);
        float ss = 0.f;
        #pragma unroll
        for (int w = 0; w < WIN; w++) {
            float v = xcT[w][t] - m;
            xcT[w][t] = v;
            ss += v * v;
        }
        invn[t] = rsqrtf(ss);
    }
    __syncthreads();
    for (int tt2 = t; tt2 < 2500; tt2 += 256) {
        int ti = tt2 / 50, tj = tt2 % 50;
        int i0 = 2 * ti, j0v = 2 * tj;
        float d00 = 0.f, d01 = 0.f, d10 = 0.f, d11 = 0.f;
        #pragma unroll
        for (int w = 0; w < WIN; w++) {
            float2 xi = *(const float2*)&xcT[w][i0];
            float2 xj = *(const float2*)&xcT[w][j0v];
            d00 = fmaf(xi.x, xj.x, d00); d01 = fmaf(xi.x, xj.y, d01);
            d10 = fmaf(xi.y, xj.x, d10); d11 = fmaf(xi.y, xj.y, d11);
        }
        float ii0 = invn[i0], ii1 = invn[i0 + 1];
        float ij0 = invn[j0v], ij1 = invn[j0v + 1];
        float e = (ti == tj) ? 1.f : 0.f;
        adjs[i0][j0v]         = 1.f - fabsf(d00 * ii0 * ij0) + e;
        adjs[i0][j0v + 1]     = 1.f - fabsf(d01 * ii0 * ij1);
        adjs[i0 + 1][j0v]     = 1.f - fabsf(d10 * ii1 * ij0);
        adjs[i0 + 1][j0v + 1] = 1.f - fabsf(d11 * ii1 * ij1) + e;
    }
    __syncthreads();
    if (t < A) {
        float s = 0.f;
        for (int j = 0; j < A; j++) s += adjs[t][j];
        dinv[t] = rsqrtf(s);
    }
    __syncthreads();
    for (int idx = t; idx < A * A; idx += 256) {
        int i = idx / A, j = idx % A;
        nadj[g * A * A + idx] = dinv[i] * adjs[i][j] * dinv[j];
    }
}

// ---------------------------------------------------------------------------
// Kernel 2: one GCN layer via split-bf16 MFMA (3-product hi/lo).
//   Z[g, :, cbase:cbase+64] = relu(S @ (X @ W[:,half]) + b[half])
// Grid (G, 2), 256 threads (4 waves; wave = one 16-col n-tile).
// M=100 -> 7 m-tiles of 16 (pad rows zeroed). K chunked by 32.
// Y stays in LDS as bf16 hi/lo, [n][k] layout. S re-staged per chunk into
// the X buffers (LDS total 63 KB). MFMA layouts per m97/m120 convention:
//   A[m=lane&15][k=quad*8+j], B[n=lane&15][k=quad*8+j] (B^T storage),
//   C/D col=lane&15, row=quad*4+reg.
// ---------------------------------------------------------------------------
__global__ __launch_bounds__(256) void k_layer(const float* __restrict__ nadj,
                                               const float* __restrict__ X,
                                               const float* __restrict__ W,
                                               const float* __restrict__ bias,
                                               float* __restrict__ Z, int K) {
    __shared__ short Xh[112 * 40], Xl[112 * 40];   // A-operand (X chunk / S chunk)
    __shared__ short Wh[64 * 40],  Wl[64 * 40];    // B-operand (W chunk), [n][k]
    __shared__ short Yh[64 * 136], Yl[64 * 136];   // Y, [n][k] k=0..127 (pad 136)

    const int g = blockIdx.x;
    const int cbase = blockIdx.y * 64;
    const int t = threadIdx.x;
    const int w = t >> 6, lane = t & 63;
    const int quad = lane >> 4, r16 = lane & 15;

    // zero: Xh/Xl pad rows 100..111; Yh/Yl k rows 112..127
    for (int e = t; e < 480; e += 256) { Xh[4000 + e] = 0; Xl[4000 + e] = 0; }
    for (int e = t; e < 1024; e += 256) {
        int n = e >> 4, k = 112 + (e & 15);
        Yh[n * 136 + k] = 0; Yl[n * 136 + k] = 0;
    }

    floatx4 acc[7];
    #pragma unroll
    for (int i = 0; i < 7; i++) acc[i] = (floatx4)0.f;

    // ---- phase A: Y = X @ W(half) ----
    const float* Xg = X + (size_t)g * A * K;
    const int nch = K >> 5;
    for (int c = 0; c < nch; c++) {
        const int k0 = c << 5;
        // stage X chunk: 100 rows x 32 k
        for (int e = t; e < 400; e += 256) {
            int r = e >> 2, q = e & 3;
            const float* gp = Xg + (size_t)r * K + k0 + q * 8;
            float4 f0 = *(const float4*)gp;
            float4 f1 = *(const float4*)(gp + 4);
            float v[8] = {f0.x, f0.y, f0.z, f0.w, f1.x, f1.y, f1.z, f1.w};
            short8 hh, ll;
            #pragma unroll
            for (int i = 0; i < 8; i++) {
                BfPair p = split1(v[i]);
                hh[i] = p.h; ll[i] = p.l;
            }
            *(short8*)&Xh[r * 40 + q * 8] = hh;
            *(short8*)&Xl[r * 40 + q * 8] = ll;
        }
        // stage W chunk: 32 k x 64 n, transposed to [n][k]
        for (int e = t; e < 512; e += 256) {
            int kk = e >> 4, n4 = (e & 15) * 4;
            float4 f = *(const float4*)(W + (size_t)(k0 + kk) * H + cbase + n4);
            float v[4] = {f.x, f.y, f.z, f.w};
            #pragma unroll
            for (int i = 0; i < 4; i++) {
                BfPair p = split1(v[i]);
                Wh[(n4 + i) * 40 + kk] = p.h;
                Wl[(n4 + i) * 40 + kk] = p.l;
            }
        }
        __syncthreads();
        short8 bh = *(const short8*)&Wh[(w * 16 + r16) * 40 + quad * 8];
        short8 bl = *(const short8*)&Wl[(w * 16 + r16) * 40 + quad * 8];
        #pragma unroll
        for (int tm = 0; tm < 7; tm++) {
            short8 ah = *(const short8*)&Xh[(tm * 16 + r16) * 40 + quad * 8];
            short8 al = *(const short8*)&Xl[(tm * 16 + r16) * 40 + quad * 8];
            acc[tm] = __builtin_amdgcn_mfma_f32_16x16x32_bf16(ah, bh, acc[tm], 0, 0, 0);
            acc[tm] = __builtin_amdgcn_mfma_f32_16x16x32_bf16(ah, bl, acc[tm], 0, 0, 0);
            acc[tm] = __builtin_amdgcn_mfma_f32_16x16x32_bf16(al, bh, acc[tm], 0, 0, 0);
        }
        __syncthreads();
    }

    // ---- epilogue A: Y -> LDS bf16 hi/lo, [n][k] ----
    const int n = w * 16 + r16;
    #pragma unroll
    for (int tm = 0; tm < 7; tm++) {
        short4v yh, yl;
        #pragma unroll
        for (int rr = 0; rr < 4; rr++) {
            BfPair p = split1(acc[tm][rr]);
            yh[rr] = p.h; yl[rr] = p.l;
        }
        *(short4v*)&Yh[n * 136 + tm * 16 + quad * 4] = yh;
        *(short4v*)&Yl[n * 136 + tm * 16 + quad * 4] = yl;
        acc[tm] = (floatx4)0.f;
    }
    __syncthreads();

    // ---- phase B: Z = relu(S @ Y + b) ----
    const float* ng = nadj + (size_t)g * A * A;
    for (int c = 0; c < 4; c++) {
        const int k0 = c << 5;
        // stage S chunk into X buffers (rows 0..99; k>=100 zero-padded)
        for (int e = t; e < 400; e += 256) {
            int r = e >> 2, q = e & 3;
            short8 hh, ll;
            #pragma unroll
            for (int i = 0; i < 8; i++) {
                int k = k0 + q * 8 + i;
                float v = (k < A) ? ng[r * A + k] : 0.f;
                BfPair p = split1(v);
                hh[i] = p.h; ll[i] = p.l;
            }
            *(short8*)&Xh[r * 40 + q * 8] = hh;
            *(short8*)&Xl[r * 40 + q * 8] = ll;
        }
        __syncthreads();
        short8 bh = *(const short8*)&Yh[n * 136 + k0 + quad * 8];
        short8 bl = *(const short8*)&Yl[n * 136 + k0 + quad * 8];
        #pragma unroll
        for (int tm = 0; tm < 7; tm++) {
            short8 ah = *(const short8*)&Xh[(tm * 16 + r16) * 40 + quad * 8];
            short8 al = *(const short8*)&Xl[(tm * 16 + r16) * 40 + quad * 8];
            acc[tm] = __builtin_amdgcn_mfma_f32_16x16x32_bf16(ah, bh, acc[tm], 0, 0, 0);
            acc[tm] = __builtin_amdgcn_mfma_f32_16x16x32_bf16(ah, bl, acc[tm], 0, 0, 0);
            acc[tm] = __builtin_amdgcn_mfma_f32_16x16x32_bf16(al, bh, acc[tm], 0, 0, 0);
        }
        __syncthreads();
    }

    const float bv = bias[cbase + n];
    #pragma unroll
    for (int tm = 0; tm < 7; tm++) {
        #pragma unroll
        for (int rr = 0; rr < 4; rr++) {
            int r = tm * 16 + quad * 4 + rr;
            if (r < A)
                Z[((size_t)g * A + r) * H + cbase + n] =
                    fmaxf(0.f, acc[tm][rr] + bv);
        }
    }
}

// ---------------------------------------------------------------------------
// Kernel 3: fused conv1(1x3)+relu+conv2(1x3). 4 cols/lane, full c-loop per
// wave (no split), weights packed in LDS [c][8], broadcast b128 reads.
// 1600 blocks x 256 thr = 6400 waves.
// ---------------------------------------------------------------------------
__global__ __launch_bounds__(256) void k_conv(const float* __restrict__ h3,
                                              const float* __restrict__ cw1,
                                              const float* __restrict__ cb1,
                                              const float* __restrict__ cw2,
                                              const float* __restrict__ cb2,
                                              float* __restrict__ out) {
    __shared__ float wbuf[H][8];     // {w0,w1,w2,b1, v0,v1,v2,0}
    const int t = threadIdx.x;
    if (t < H) {
        *(float4*)&wbuf[t][0] = make_float4(cw1[3 * t], cw1[3 * t + 1], cw1[3 * t + 2], cb1[t]);
        *(float4*)&wbuf[t][4] = make_float4(cw2[3 * t], cw2[3 * t + 1], cw2[3 * t + 2], 0.f);
    }
    __syncthreads();

    const int wave = t >> 6, lane = t & 63;
    const int n = blockIdx.x * 8 + wave * 2 + (lane >> 5);
    const int q = lane & 31;
    const int j0 = q * 4;
    const float* hr = h3 + (size_t)n * H;

    float hh[8];   // h[j0-2 .. j0+5], zero-padded (conv1 padding)
    if (q == 0) {
        float4 a  = *(const float4*)(hr);
        float2 b2 = *(const float2*)(hr + 4);
        hh[0] = 0.f;  hh[1] = 0.f;  hh[2] = a.x;  hh[3] = a.y;
        hh[4] = a.z;  hh[5] = a.w;  hh[6] = b2.x; hh[7] = b2.y;
    } else if (q == 31) {
        float2 b2 = *(const float2*)(hr + 122);
        float4 a  = *(const float4*)(hr + 124);
        hh[0] = b2.x; hh[1] = b2.y; hh[2] = a.x;  hh[3] = a.y;
        hh[4] = a.z;  hh[5] = a.w;  hh[6] = 0.f;  hh[7] = 0.f;
    } else {
        float4 a  = *(const float4*)(hr + j0 - 2);
        float4 b4 = *(const float4*)(hr + j0 + 2);
        hh[0] = a.x;  hh[1] = a.y;  hh[2] = a.z;  hh[3] = a.w;
        hh[4] = b4.x; hh[5] = b4.y; hh[6] = b4.z; hh[7] = b4.w;
    }
    const float mlo = (q == 0)  ? 0.f : 1.f;   // conv2 pad: T[-1]=0
    const float mhi = (q == 31) ? 0.f : 1.f;   // T[128]=0

    float acc[4] = {0.f, 0.f, 0.f, 0.f};
    #pragma unroll 4
    for (int c = 0; c < H; c++) {
        float4 wA = *(const float4*)&wbuf[c][0];  // w0,w1,w2,b
        float4 wB = *(const float4*)&wbuf[c][4];  // v0,v1,v2,-
        float tt[6];   // conv1 output at j = j0-1+m
        #pragma unroll
        for (int m = 0; m < 6; m++)
            tt[m] = fmaxf(0.f, fmaf(wA.z, hh[m + 2],
                               fmaf(wA.y, hh[m + 1],
                               fmaf(wA.x, hh[m], wA.w))));
        tt[0] *= mlo;
        tt[5] *= mhi;
        #pragma unroll
        for (int p = 0; p < 4; p++)
            acc[p] = fmaf(wB.x, tt[p],
                     fmaf(wB.y, tt[p + 1],
                     fmaf(wB.z, tt[p + 2], acc[p])));
    }
    const float c2b = cb2[0];
    *(float4*)(out + (size_t)n * H + j0) =
        make_float4(acc[0] + c2b, acc[1] + c2b, acc[2] + c2b, acc[3] + c2b);
}

// ---------------------------------------------------------------------------
extern "C" void kernel_launch(void* const* d_in, const int* in_sizes, int n_in,
                              void* d_out, int out_size, void* d_ws, size_t ws_size,
                              hipStream_t stream) {
    const float* x   = (const float*)d_in[0];
    const float* W1  = (const float*)d_in[1];
    const float* b1  = (const float*)d_in[2];
    const float* W2  = (const float*)d_in[3];
    const float* b2  = (const float*)d_in[4];
    const float* W3  = (const float*)d_in[5];
    const float* b3  = (const float*)d_in[6];
    const float* cw1 = (const float*)d_in[7];
    const float* cb1 = (const float*)d_in[8];
    const float* cw2 = (const float*)d_in[9];
    const float* cb2 = (const float*)d_in[10];
    float* out = (float*)d_out;

    float* ws   = (float*)d_ws;
    float* nadj = ws;                         // G*A*A   = 1,280,000 floats
    float* bufA = nadj + (size_t)G * A * A;   // NROWS*H = 1,638,400 floats
    float* bufB = bufA + (size_t)NROWS * H;

    k_nadj<<<G, 256, 0, stream>>>(x, nadj);

    k_layer<<<dim3(G, 2), 256, 0, stream>>>(nadj, x,    W1, b1, bufA, K1);
    k_layer<<<dim3(G, 2), 256, 0, stream>>>(nadj, bufA, W2, b2, bufB, H);
    k_layer<<<dim3(G, 2), 256, 0, stream>>>(nadj, bufB, W3, b3, bufA, H);

    k_conv<<<NROWS / 8, 256, 0, stream>>>(bufA, cw1, cb1, cw2, cb2, out);
}